// Round 16
// baseline (178.700 us; speedup 1.0000x reference)
//
#include <hip/hip_runtime.h>
#include <cstdint>
#include <cstddef>

typedef __bf16 bf16;
typedef __attribute__((ext_vector_type(8))) __bf16 bf16x8;
typedef __attribute__((ext_vector_type(4))) __bf16 bf16x4;
typedef __attribute__((ext_vector_type(4))) float f32x4;
typedef __attribute__((ext_vector_type(4))) int i32x4;

#define ADIM 1024
#define ASEQ 2048
#define ABATCH 8

__device__ __forceinline__ void gload_lds16(const void* g, void* l) {
  __builtin_amdgcn_global_load_lds(
      (const __attribute__((address_space(1))) void*)g,
      (__attribute__((address_space(3))) void*)l,
      16, 0, 0);
}

__device__ __forceinline__ f32x4 mfma16(bf16x8 a, bf16x8 b, f32x4 c) {
  return __builtin_amdgcn_mfma_f32_16x16x32_bf16(a, b, c, 0, 0, 0);
}
__device__ __forceinline__ i32x4 mfma8i(i32x4 a, i32x4 b, i32x4 c) {
  return __builtin_amdgcn_mfma_i32_16x16x64_i8(a, b, c, 0, 0, 0);
}

// ------- prep: transpose weights to B^T bf16 (coalesced both sides) -------
__global__ __launch_bounds__(256) void k_prep_w(
    const float* __restrict__ Wq, const float* __restrict__ Wk,
    const float* __restrict__ Wv, const float* __restrict__ Wo,
    bf16* __restrict__ WcT, bf16* __restrict__ WoT) {
  const int b = blockIdx.x;
  const int which = b >> 8, t = b & 255;
  const int n0 = (t & 15) * 64, k0 = (t >> 4) * 64;
  const float* W = (which == 0) ? Wq : (which == 1) ? Wk : (which == 2) ? Wv : Wo;
  bf16* out = (which < 3) ? (WcT + (size_t)which * ADIM * ADIM) : WoT;

  __shared__ float tile[64][69];
  const int r = threadIdx.x >> 4, c4 = (threadIdx.x & 15) * 4;
#pragma unroll
  for (int p = 0; p < 4; ++p) {
    float4 f = *(const float4*)&W[(size_t)(k0 + p * 16 + r) * ADIM + n0 + c4];
    tile[p * 16 + r][c4 + 0] = f.x;
    tile[p * 16 + r][c4 + 1] = f.y;
    tile[p * 16 + r][c4 + 2] = f.z;
    tile[p * 16 + r][c4 + 3] = f.w;
  }
  __syncthreads();
#pragma unroll
  for (int p = 0; p < 4; ++p) {
    const int nn = p * 16 + r;
    bf16x4 o;
#pragma unroll
    for (int j = 0; j < 4; ++j) o[j] = (bf16)tile[c4 + j][nn];
    *(bf16x4*)&out[(size_t)(n0 + nn) * ADIM + k0 + c4] = o;
  }
}

// ---- quantize rows to i8 + per-row scale. One 64-lane wave per row. ----
__global__ __launch_bounds__(256) void k_q(
    const float* __restrict__ x, const bf16* __restrict__ WcT,
    const bf16* __restrict__ WoT,
    signed char* __restrict__ Xq, float* __restrict__ sx,
    signed char* __restrict__ WcQ, float* __restrict__ swc,
    signed char* __restrict__ WoQ, float* __restrict__ swo) {
  const int row = blockIdx.x * 4 + (threadIdx.x >> 6);
  const int l = threadIdx.x & 63;
  float v[16];
  if (row < 16384) {
    const float4* p = (const float4*)&x[(size_t)row * ADIM + l * 16];
#pragma unroll
    for (int g = 0; g < 4; ++g) {
      float4 f = p[g];
      v[g * 4 + 0] = f.x; v[g * 4 + 1] = f.y; v[g * 4 + 2] = f.z; v[g * 4 + 3] = f.w;
    }
  } else {
    const bf16* src = (row < 19456)
        ? (WcT + (size_t)(row - 16384) * ADIM)
        : (WoT + (size_t)(row - 19456) * ADIM);
    const bf16x8* p = (const bf16x8*)&src[l * 16];
#pragma unroll
    for (int g = 0; g < 2; ++g) {
      bf16x8 f = p[g];
#pragma unroll
      for (int e = 0; e < 8; ++e) v[g * 8 + e] = (float)f[e];
    }
  }
  float m = 0.f;
#pragma unroll
  for (int e = 0; e < 16; ++e) m = fmaxf(m, fabsf(v[e]));
#pragma unroll
  for (int off = 32; off >= 1; off >>= 1) m = fmaxf(m, __shfl_xor(m, off));
  m = fmaxf(m, 1e-20f);
  const float inv = 127.f / m;
  i32x4 pk;
#pragma unroll
  for (int g = 0; g < 4; ++g) {
    int word = 0;
#pragma unroll
    for (int e = 0; e < 4; ++e) {
      int q = __float2int_rn(v[g * 4 + e] * inv);
      q = max(-127, min(127, q));
      word |= (q & 255) << (e * 8);
    }
    pk[g] = word;
  }
  if (row < 16384) {
    *(i32x4*)&Xq[(size_t)row * ADIM + l * 16] = pk;
    if (l == 0) sx[row] = m / 127.f;
  } else if (row < 19456) {
    *(i32x4*)&WcQ[(size_t)(row - 16384) * ADIM + l * 16] = pk;
    if (l == 0) swc[row - 16384] = m / 127.f;
  } else {
    *(i32x4*)&WoQ[(size_t)(row - 19456) * ADIM + l * 16] = pk;
    if (l == 0) swo[row - 19456] = m / 127.f;
  }
}

// ---- quantize R (attn output, bf16) rows -> Rq i8 + sxr ----
__global__ __launch_bounds__(256) void k_qr(
    const bf16* __restrict__ Rb, signed char* __restrict__ Rq,
    float* __restrict__ sxr) {
  const int row = blockIdx.x * 4 + (threadIdx.x >> 6);
  const int l = threadIdx.x & 63;
  float v[16];
  const bf16x8* p = (const bf16x8*)&Rb[(size_t)row * ADIM + l * 16];
#pragma unroll
  for (int g = 0; g < 2; ++g) {
    bf16x8 f = p[g];
#pragma unroll
    for (int e = 0; e < 8; ++e) v[g * 8 + e] = (float)f[e];
  }
  float m = 0.f;
#pragma unroll
  for (int e = 0; e < 16; ++e) m = fmaxf(m, fabsf(v[e]));
#pragma unroll
  for (int off = 32; off >= 1; off >>= 1) m = fmaxf(m, __shfl_xor(m, off));
  m = fmaxf(m, 1e-20f);
  const float inv = 127.f / m;
  i32x4 pk;
#pragma unroll
  for (int g = 0; g < 4; ++g) {
    int word = 0;
#pragma unroll
    for (int e = 0; e < 4; ++e) {
      int q = __float2int_rn(v[g * 4 + e] * inv);
      q = max(-127, min(127, q));
      word |= (q & 255) << (e * 8);
    }
    pk[g] = word;
  }
  *(i32x4*)&Rq[(size_t)row * ADIM + l * 16] = pk;
  if (l == 0) sxr[row] = m / 127.f;
}

// ====== i8 GEMM: 256x256, BK=128B, A:3-slot/B:2-slot ring, 160 KiB LDS ======
// r13 swizzle (8-slot, conflict-free) + r7 counted ledger (proven correct;
// r7's regression was the launch_bounds(512,4) spill, avoided here):
//  prologue A0,B0,A1 (12 gloads); vmcnt(4) retires A0,B0, A1 flying.
//  step t: read sA[t%3], sB[t&1]; stage B(t+1)->(t+1)&1 then A(t+2)->(t+2)%3
//  (8 gloads); end vmcnt(4)+barrier retires A(t+1),B(t+1) (oldest 8 of 12),
//  leaves A(t+2) in flight. Never drains to 0 mid-loop.
//  WAR: each staged slot last read one barrier-terminated step earlier.
//  Tail dummies target slots never read again (checked for KT=8).
// MODE 0: QKV dequant epilogue -> Q/K/Vt bf16. MODE 1: out fp32 = deq + bias0.
template<int MODE>
__global__ __launch_bounds__(512, 2) void k_gi8(
    const signed char* __restrict__ A, const signed char* __restrict__ BT,
    const float* __restrict__ sa, const float* __restrict__ sb,
    const float* __restrict__ bias0, const float* __restrict__ bias1,
    const float* __restrict__ bias2,
    bf16* __restrict__ Qo, bf16* __restrict__ Ko, bf16* __restrict__ Vto,
    float* __restrict__ outF, int ntn)
{
  constexpr int K = 1024;           // bytes per row
  constexpr int KT = 8;             // steps of BK=128 bytes
  const int nwg = gridDim.x;
  const int cpx = nwg >> 3;
  const int flat = blockIdx.x;
  const int sw = (flat & 7) * cpx + (flat >> 3);
  const int bx = sw % ntn, by = sw / ntn;
  const int m0 = by * 256, n0 = bx * 256;

  const int tid = threadIdx.x;
  const int l = tid & 63, w = tid >> 6;
  const int wm = w >> 2, wn = w & 3;
  const int lr = l & 15, kg = l >> 4;

  __shared__ alignas(16) signed char sA[3][256 * 128];   // 96 KiB
  __shared__ alignas(16) signed char sB[2][256 * 128];   // 64 KiB -> 160 KiB

  i32x4 acc[8][4] = {};

  int oA[8], oB[4];
#pragma unroll
  for (int i = 0; i < 8; ++i) {
    int r = wm * 128 + i * 16 + lr;
    oA[i] = (r * 8 + (kg ^ (r & 7))) * 16;
  }
#pragma unroll
  for (int j = 0; j < 4; ++j) {
    int r = wn * 64 + j * 16 + lr;
    oB[j] = (r * 8 + (kg ^ (r & 7))) * 16;
  }

  auto stA = [&](int sp, int kt, int chunk) {
    int s = chunk * 512 + tid;
    int prow = s >> 3, ps = s & 7;
    int lc = ps ^ (prow & 7);
    gload_lds16(A + (size_t)(m0 + prow) * K + kt * 128 + lc * 16,
                &sA[sp][(size_t)s * 16]);
  };
  auto stB = [&](int sp, int kt, int chunk) {
    int s = chunk * 512 + tid;
    int prow = s >> 3, ps = s & 7;
    int lc = ps ^ (prow & 7);
    gload_lds16(BT + (size_t)(n0 + prow) * K + kt * 128 + lc * 16,
                &sB[sp][(size_t)s * 16]);
  };

  // prologue: A0, B0, A1 (12 gloads); vmcnt(4) -> A0,B0 resident, A1 flying
#pragma unroll
  for (int ch = 0; ch < 4; ++ch) stA(0, 0, ch);
#pragma unroll
  for (int ch = 0; ch < 4; ++ch) stB(0, 0, ch);
#pragma unroll
  for (int ch = 0; ch < 4; ++ch) stA(1, 1, ch);
  asm volatile("s_waitcnt vmcnt(4)\n\ts_barrier" ::: "memory");

  for (int t = 0; t < KT; ++t) {
    const int sa_ = t % 3, sb_ = t & 1;
    const char* bA = (const char*)&sA[sa_][0];
    const char* bB = (const char*)&sB[sb_][0];

    i32x4 af[8], bfr[4];
#pragma unroll
    for (int i = 0; i < 8; ++i) af[i] = *(const i32x4*)(bA + oA[i]);
#pragma unroll
    for (int j = 0; j < 4; ++j) bfr[j] = *(const i32x4*)(bB + oB[j]);

    // stage B(t+1) first, A(t+2) second (issue order = ledger order)
    const int tb = (t + 1 < KT) ? t + 1 : t;   // dummy tail (slot never re-read)
    const int ta = (t + 2 < KT) ? t + 2 : t;
#pragma unroll
    for (int ch = 0; ch < 4; ++ch) stB((t + 1) & 1, tb, ch);
#pragma unroll
    for (int ch = 0; ch < 4; ++ch) stA((t + 2) % 3, ta, ch);

    __builtin_amdgcn_s_setprio(1);
#pragma unroll
    for (int i = 0; i < 8; ++i)
#pragma unroll
      for (int j = 0; j < 4; ++j)
        acc[i][j] = mfma8i(af[i], bfr[j], acc[i][j]);
    __builtin_amdgcn_s_setprio(0);

#pragma unroll
    for (int i = 0; i < 8; ++i) af[i] = *(const i32x4*)(bA + (oA[i] ^ 64));
#pragma unroll
    for (int j = 0; j < 4; ++j) bfr[j] = *(const i32x4*)(bB + (oB[j] ^ 64));

    __builtin_amdgcn_s_setprio(1);
#pragma unroll
    for (int i = 0; i < 8; ++i)
#pragma unroll
      for (int j = 0; j < 4; ++j)
        acc[i][j] = mfma8i(af[i], bfr[j], acc[i][j]);
    __builtin_amdgcn_s_setprio(0);

    asm volatile("s_waitcnt vmcnt(4)\n\ts_barrier" ::: "memory");
  }
  asm volatile("s_waitcnt vmcnt(0)" ::: "memory");   // drain tail dummies

  // ---- dequant epilogue ----
  const int cb = n0 >> 10;
#pragma unroll
  for (int i = 0; i < 8; ++i) {
#pragma unroll
    for (int jj = 0; jj < 4; ++jj) {
      const int n = n0 + wn * 64 + jj * 16 + lr;
      const int m0r = m0 + wm * 128 + i * 16 + kg * 4;
      const float sbn = sb[n];
      const float4 s4 = *(const float4*)&sa[m0r];
      float de[4];
      de[0] = (float)acc[i][jj][0] * s4.x * sbn;
      de[1] = (float)acc[i][jj][1] * s4.y * sbn;
      de[2] = (float)acc[i][jj][2] * s4.z * sbn;
      de[3] = (float)acc[i][jj][3] * s4.w * sbn;
      if (MODE == 0) {
        const int nn = n & 1023;
        if (cb == 0) {
          const float b_ = bias0[nn];
#pragma unroll
          for (int r = 0; r < 4; ++r)
            Qo[(size_t)(m0r + r) * ADIM + nn] = (bf16)(de[r] + b_);
        } else if (cb == 1) {
          const float b_ = bias1[nn];
#pragma unroll
          for (int r = 0; r < 4; ++r) {
            float v = de[r] + b_;
            Ko[(size_t)(m0r + r) * ADIM + nn] = (bf16)(v > 0.f ? v + 1.f : __expf(v));
          }
        } else {
          const float b_ = bias2[nn];
          const int bb = m0r >> 11, t0c = m0r & 2047;
          bf16x4 pk;
#pragma unroll
          for (int r = 0; r < 4; ++r) pk[r] = (bf16)(de[r] + b_);
          *(bf16x4*)&Vto[((size_t)bb * ADIM + nn) * ASEQ + t0c] = pk;
        }
      } else {
        const float b_ = bias0[n];
#pragma unroll
        for (int r = 0; r < 4; ++r)
          outF[(size_t)(m0r + r) * ADIM + n] = de[r] + b_;
      }
    }
  }
}

// ------ windowed decay attention, 3-slot counted-vmcnt rings (r14-proven) ------
__global__ __launch_bounds__(256) void k_attn(
    const bf16* __restrict__ Qg, const bf16* __restrict__ Kg,
    const bf16* __restrict__ Vt, bf16* __restrict__ Rb,
    const float* __restrict__ decay_param)
{
  const int b = blockIdx.y;
  const int T0 = blockIdx.x * 64;
  const int tid = threadIdx.x;
  const int l = tid & 63, w = tid >> 6;
  const int lr = l & 15, lk = (l >> 4) * 8;

  const float dp = decay_param[0];
  const float decay = 1.f / (1.f + __expf(-dp));
  const float l2d = __log2f(decay);

  __shared__ alignas(16) bf16 lQ[3][64 * 32];
  __shared__ alignas(16) bf16 lK[3][128 * 32];
  __shared__ alignas(16) bf16 lV[3][128 * 32];
  __shared__ alignas(16) bf16 lP[64 * 136];

  const bf16* Qb = Qg + (size_t)(b * ASEQ + T0) * ADIM;

  auto stageQK = [&](int buf, int k0) {
    {
      const bf16* g = Qb + (size_t)(w * 16 + (l >> 2)) * ADIM + k0 + (l & 3) * 8;
      gload_lds16(g, &lQ[buf][w * 16 * 32]);
    }
#pragma unroll
    for (int cc = 0; cc < 2; ++cc) {
      int c = 2 * w + cc;
      int sg = T0 - 64 + c * 16 + (l >> 2);
      if (sg < 0) sg = 0;
      const bf16* g = Kg + (size_t)(b * ASEQ + sg) * ADIM + k0 + (l & 3) * 8;
      gload_lds16(g, &lK[buf][c * 16 * 32]);
    }
  };

  f32x4 sc[4][2] = {};
  stageQK(0, 0);
  stageQK(1, 32);
  asm volatile("s_waitcnt vmcnt(3)\n\ts_barrier" ::: "memory");

  for (int kt = 0; kt < 32; ++kt) {
    const int cur = kt % 3;
    bf16x8 af[4], bfr[2];
#pragma unroll
    for (int i = 0; i < 4; ++i)
      af[i] = *(const bf16x8*)&lQ[cur][(i * 16 + lr) * 32 + lk];
#pragma unroll
    for (int j = 0; j < 2; ++j)
      bfr[j] = *(const bf16x8*)&lK[cur][(w * 32 + j * 16 + lr) * 32 + lk];

    const int tp = (kt + 2 < 32) ? kt + 2 : kt;
    stageQK((kt + 2) % 3, tp * 32);

#pragma unroll
    for (int i = 0; i < 4; ++i)
#pragma unroll
      for (int j = 0; j < 2; ++j)
        sc[i][j] = mfma16(af[i], bfr[j], sc[i][j]);

    asm volatile("s_waitcnt vmcnt(3)\n\ts_barrier" ::: "memory");
  }

  const int er = (l >> 4) * 4, ec = l & 15;
#pragma unroll
  for (int i = 0; i < 4; ++i)
#pragma unroll
    for (int j = 0; j < 2; ++j)
#pragma unroll
      for (int r = 0; r < 4; ++r) {
        int tl = i * 16 + er + r;
        int sl = w * 32 + j * 16 + ec;
        int sg = T0 - 64 + sl;
        int delta = (T0 + tl) - 1 - sg;
        float wgt = (delta >= 0 && delta < 64 && sg >= 0)
                        ? exp2f((float)delta * l2d) : 0.f;
        lP[tl * 136 + sl] = (bf16)(sc[i][j][r] * wgt);
      }

  auto stageV = [&](int buf, int g) {
    int nc = g >> 2, ks = g & 3;
#pragma unroll
    for (int cc = 0; cc < 2; ++cc) {
      int c = 2 * w + cc;
      int drow = nc * 128 + c * 16 + (l >> 2);
      int scol = T0 - 64 + ks * 32 + (l & 3) * 8;
      if (scol < 0) scol = 0;
      const bf16* gv = Vt + ((size_t)b * ADIM + drow) * ASEQ + scol;
      gload_lds16(gv, &lV[buf][c * 16 * 32]);
    }
  };

  stageV(0, 0);
  stageV(1, 1);
  asm volatile("s_waitcnt vmcnt(2) lgkmcnt(0)\n\ts_barrier" ::: "memory");

  f32x4 o[4][2] = {};
  for (int g = 0; g < 32; ++g) {
    const int cur = g % 3;
    const int nc = g >> 2, ks = g & 3;
    bf16x8 af[4], bfr[2];
#pragma unroll
    for (int i = 0; i < 4; ++i)
      af[i] = *(const bf16x8*)&lP[(i * 16 + lr) * 136 + ks * 32 + lk];
#pragma unroll
    for (int j = 0; j < 2; ++j)
      bfr[j] = *(const bf16x8*)&lV[cur][(w * 32 + j * 16 + lr) * 32 + lk];

    const int gp = (g + 2 < 32) ? g + 2 : g;
    stageV((g + 2) % 3, gp);

#pragma unroll
    for (int i = 0; i < 4; ++i)
#pragma unroll
      for (int j = 0; j < 2; ++j)
        o[i][j] = mfma16(af[i], bfr[j], o[i][j]);

    if (ks == 3) {
#pragma unroll
      for (int i = 0; i < 4; ++i)
#pragma unroll
        for (int j = 0; j < 2; ++j) {
#pragma unroll
          for (int r = 0; r < 4; ++r) {
            int tl = i * 16 + er + r;
            int dl = nc * 128 + w * 32 + j * 16 + ec;
            Rb[(size_t)(b * ASEQ + T0 + tl) * ADIM + dl] = (bf16)o[i][j][r];
          }
#pragma unroll
          for (int r = 0; r < 4; ++r) o[i][j][r] = 0.f;
        }
    }
    asm volatile("s_waitcnt vmcnt(2)\n\ts_barrier" ::: "memory");
  }
  asm volatile("s_waitcnt vmcnt(0)" ::: "memory");
}

extern "C" void kernel_launch(void* const* d_in, const int* in_sizes, int n_in,
                              void* d_out, int out_size, void* d_ws, size_t ws_size,
                              hipStream_t stream) {
  const float* x  = (const float*)d_in[0];
  const float* Wq = (const float*)d_in[1];
  const float* bq = (const float*)d_in[2];
  const float* Wk = (const float*)d_in[3];
  const float* bk = (const float*)d_in[4];
  const float* Wv = (const float*)d_in[5];
  const float* bv = (const float*)d_in[6];
  const float* Wo = (const float*)d_in[7];
  const float* bo = (const float*)d_in[8];
  const float* dp = (const float*)d_in[9];
  float* out = (float*)d_out;

  char* ws = (char*)d_ws;
  signed char* Xq  = (signed char*)(ws + ((size_t)0 << 20));   // 16 MB
  signed char* Rq  = Xq;                                       // alias (Xq dead)
  float*       sx  = (float*)(ws + ((size_t)16 << 20));        // 64 KB
  float*       sxr = sx;
  signed char* WcQ = (signed char*)(ws + ((size_t)17 << 20));  // 3 MB
  float*       swc = (float*)(ws + ((size_t)20 << 20));        // 12 KB
  signed char* WoQ = (signed char*)(ws + ((size_t)21 << 20));  // 1 MB
  float*       swo = (float*)(ws + ((size_t)22 << 20));        // 4 KB
  bf16* Qb  = (bf16*)(ws + ((size_t)32 << 20));
  bf16* Kb  = (bf16*)(ws + ((size_t)64 << 20));
  bf16* Vtb = (bf16*)(ws + ((size_t)96 << 20));                // [8][1024][2048]
  bf16* Rbb = (bf16*)(ws + ((size_t)128 << 20));
  bf16* WcT = (bf16*)(ws + ((size_t)160 << 20));               // [3072][1024] bf16
  bf16* WoT = (bf16*)(ws + ((size_t)166 << 20));               // [1024][1024] bf16

  k_prep_w<<<1024, 256, 0, stream>>>(Wq, Wk, Wv, Wo, WcT, WoT);
  k_q<<<5120, 256, 0, stream>>>(x, WcT, WoT, Xq, sx, WcQ, swc, WoQ, swo);
  k_gi8<0><<<768, 512, 0, stream>>>(
      Xq, WcQ, sx, swc, bq, bk, bv, Qb, Kb, Vtb, nullptr, 12);
  k_attn<<<dim3(32, 8), 256, 0, stream>>>(Qb, Kb, Vtb, Rbb, dp);
  k_qr<<<4096, 256, 0, stream>>>(Rbb, Rq, sxr);
  k_gi8<1><<<256, 512, 0, stream>>>(
      Rq, WoQ, sxr, swo, bo, nullptr, nullptr, nullptr, nullptr, nullptr, out, 4);
}

// Round 17
// 174.778 us; speedup vs baseline: 1.0224x; 1.0224x over previous
//
#include <hip/hip_runtime.h>
#include <cstdint>
#include <cstddef>

typedef __bf16 bf16;
typedef __attribute__((ext_vector_type(8))) __bf16 bf16x8;
typedef __attribute__((ext_vector_type(4))) __bf16 bf16x4;
typedef __attribute__((ext_vector_type(4))) float f32x4;
typedef __attribute__((ext_vector_type(4))) int i32x4;

#define ADIM 1024
#define ASEQ 2048
#define ABATCH 8

__device__ __forceinline__ void gload_lds16(const void* g, void* l) {
  __builtin_amdgcn_global_load_lds(
      (const __attribute__((address_space(1))) void*)g,
      (__attribute__((address_space(3))) void*)l,
      16, 0, 0);
}

__device__ __forceinline__ f32x4 mfma16(bf16x8 a, bf16x8 b, f32x4 c) {
  return __builtin_amdgcn_mfma_f32_16x16x32_bf16(a, b, c, 0, 0, 0);
}
__device__ __forceinline__ i32x4 mfma8i(i32x4 a, i32x4 b, i32x4 c) {
  return __builtin_amdgcn_mfma_i32_16x16x64_i8(a, b, c, 0, 0, 0);
}

// ------- prep: transpose weights to B^T bf16 (coalesced both sides) -------
__global__ __launch_bounds__(256) void k_prep_w(
    const float* __restrict__ Wq, const float* __restrict__ Wk,
    const float* __restrict__ Wv, const float* __restrict__ Wo,
    bf16* __restrict__ WcT, bf16* __restrict__ WoT) {
  const int b = blockIdx.x;
  const int which = b >> 8, t = b & 255;
  const int n0 = (t & 15) * 64, k0 = (t >> 4) * 64;
  const float* W = (which == 0) ? Wq : (which == 1) ? Wk : (which == 2) ? Wv : Wo;
  bf16* out = (which < 3) ? (WcT + (size_t)which * ADIM * ADIM) : WoT;

  __shared__ float tile[64][69];
  const int r = threadIdx.x >> 4, c4 = (threadIdx.x & 15) * 4;
#pragma unroll
  for (int p = 0; p < 4; ++p) {
    float4 f = *(const float4*)&W[(size_t)(k0 + p * 16 + r) * ADIM + n0 + c4];
    tile[p * 16 + r][c4 + 0] = f.x;
    tile[p * 16 + r][c4 + 1] = f.y;
    tile[p * 16 + r][c4 + 2] = f.z;
    tile[p * 16 + r][c4 + 3] = f.w;
  }
  __syncthreads();
#pragma unroll
  for (int p = 0; p < 4; ++p) {
    const int nn = p * 16 + r;
    bf16x4 o;
#pragma unroll
    for (int j = 0; j < 4; ++j) o[j] = (bf16)tile[c4 + j][nn];
    *(bf16x4*)&out[(size_t)(n0 + nn) * ADIM + k0 + c4] = o;
  }
}

// ---- quantize rows to i8 + per-row scale. One 64-lane wave per row. ----
__global__ __launch_bounds__(256) void k_q(
    const float* __restrict__ x, const bf16* __restrict__ WcT,
    const bf16* __restrict__ WoT,
    signed char* __restrict__ Xq, float* __restrict__ sx,
    signed char* __restrict__ WcQ, float* __restrict__ swc,
    signed char* __restrict__ WoQ, float* __restrict__ swo) {
  const int row = blockIdx.x * 4 + (threadIdx.x >> 6);
  const int l = threadIdx.x & 63;
  float v[16];
  if (row < 16384) {
    const float4* p = (const float4*)&x[(size_t)row * ADIM + l * 16];
#pragma unroll
    for (int g = 0; g < 4; ++g) {
      float4 f = p[g];
      v[g * 4 + 0] = f.x; v[g * 4 + 1] = f.y; v[g * 4 + 2] = f.z; v[g * 4 + 3] = f.w;
    }
  } else {
    const bf16* src = (row < 19456)
        ? (WcT + (size_t)(row - 16384) * ADIM)
        : (WoT + (size_t)(row - 19456) * ADIM);
    const bf16x8* p = (const bf16x8*)&src[l * 16];
#pragma unroll
    for (int g = 0; g < 2; ++g) {
      bf16x8 f = p[g];
#pragma unroll
      for (int e = 0; e < 8; ++e) v[g * 8 + e] = (float)f[e];
    }
  }
  float m = 0.f;
#pragma unroll
  for (int e = 0; e < 16; ++e) m = fmaxf(m, fabsf(v[e]));
#pragma unroll
  for (int off = 32; off >= 1; off >>= 1) m = fmaxf(m, __shfl_xor(m, off));
  m = fmaxf(m, 1e-20f);
  const float inv = 127.f / m;
  i32x4 pk;
#pragma unroll
  for (int g = 0; g < 4; ++g) {
    int word = 0;
#pragma unroll
    for (int e = 0; e < 4; ++e) {
      int q = __float2int_rn(v[g * 4 + e] * inv);
      q = max(-127, min(127, q));
      word |= (q & 255) << (e * 8);
    }
    pk[g] = word;
  }
  if (row < 16384) {
    *(i32x4*)&Xq[(size_t)row * ADIM + l * 16] = pk;
    if (l == 0) sx[row] = m / 127.f;
  } else if (row < 19456) {
    *(i32x4*)&WcQ[(size_t)(row - 16384) * ADIM + l * 16] = pk;
    if (l == 0) swc[row - 16384] = m / 127.f;
  } else {
    *(i32x4*)&WoQ[(size_t)(row - 19456) * ADIM + l * 16] = pk;
    if (l == 0) swo[row - 19456] = m / 127.f;
  }
}

// ---- quantize R (attn output, bf16) rows -> Rq i8 + sxr ----
__global__ __launch_bounds__(256) void k_qr(
    const bf16* __restrict__ Rb, signed char* __restrict__ Rq,
    float* __restrict__ sxr) {
  const int row = blockIdx.x * 4 + (threadIdx.x >> 6);
  const int l = threadIdx.x & 63;
  float v[16];
  const bf16x8* p = (const bf16x8*)&Rb[(size_t)row * ADIM + l * 16];
#pragma unroll
  for (int g = 0; g < 2; ++g) {
    bf16x8 f = p[g];
#pragma unroll
    for (int e = 0; e < 8; ++e) v[g * 8 + e] = (float)f[e];
  }
  float m = 0.f;
#pragma unroll
  for (int e = 0; e < 16; ++e) m = fmaxf(m, fabsf(v[e]));
#pragma unroll
  for (int off = 32; off >= 1; off >>= 1) m = fmaxf(m, __shfl_xor(m, off));
  m = fmaxf(m, 1e-20f);
  const float inv = 127.f / m;
  i32x4 pk;
#pragma unroll
  for (int g = 0; g < 4; ++g) {
    int word = 0;
#pragma unroll
    for (int e = 0; e < 4; ++e) {
      int q = __float2int_rn(v[g * 4 + e] * inv);
      q = max(-127, min(127, q));
      word |= (q & 255) << (e * 8);
    }
    pk[g] = word;
  }
  *(i32x4*)&Rq[(size_t)row * ADIM + l * 16] = pk;
  if (l == 0) sxr[row] = m / 127.f;
}

// ====== i8 GEMM core: 256x256 tile, BK=128B dbuf, 1 fence/step (r13/r15-proven) ======
// MODE 0: QKV dequant epilogue -> Q/K/Vt bf16. MODE 1: out fp32 = deq + bias0.
template<int MODE>
__global__ __launch_bounds__(512, 2) void k_gi8(
    const signed char* __restrict__ A, const signed char* __restrict__ BT,
    const float* __restrict__ sa, const float* __restrict__ sb,
    const float* __restrict__ bias0, const float* __restrict__ bias1,
    const float* __restrict__ bias2,
    bf16* __restrict__ Qo, bf16* __restrict__ Ko, bf16* __restrict__ Vto,
    float* __restrict__ outF, int ntn)
{
  constexpr int K = 1024;           // bytes per row
  constexpr int KT = 8;             // steps of BK=128 bytes
  const int nwg = gridDim.x;
  const int cpx = nwg >> 3;
  const int flat = blockIdx.x;
  const int sw = (flat & 7) * cpx + (flat >> 3);
  const int bx = sw % ntn, by = sw / ntn;
  const int m0 = by * 256, n0 = bx * 256;

  const int tid = threadIdx.x;
  const int l = tid & 63, w = tid >> 6;
  const int wm = w >> 2, wn = w & 3;
  const int lr = l & 15, kg = l >> 4;

  __shared__ alignas(16) signed char sA[2][256 * 128];   // 64 KiB
  __shared__ alignas(16) signed char sB[2][256 * 128];   // 64 KiB

  i32x4 acc[8][4] = {};

  int oA[8], oB[4];
#pragma unroll
  for (int i = 0; i < 8; ++i) {
    int r = wm * 128 + i * 16 + lr;
    oA[i] = (r * 8 + (kg ^ (r & 7))) * 16;
  }
#pragma unroll
  for (int j = 0; j < 4; ++j) {
    int r = wn * 64 + j * 16 + lr;
    oB[j] = (r * 8 + (kg ^ (r & 7))) * 16;
  }

  auto stA = [&](int c, int kt, int chunk) {
    int s = chunk * 512 + tid;
    int prow = s >> 3, ps = s & 7;
    int lc = ps ^ (prow & 7);
    gload_lds16(A + (size_t)(m0 + prow) * K + kt * 128 + lc * 16,
                &sA[c][(size_t)s * 16]);
  };
  auto stB = [&](int c, int kt, int chunk) {
    int s = chunk * 512 + tid;
    int prow = s >> 3, ps = s & 7;
    int lc = ps ^ (prow & 7);
    gload_lds16(BT + (size_t)(n0 + prow) * K + kt * 128 + lc * 16,
                &sB[c][(size_t)s * 16]);
  };

#pragma unroll
  for (int ch = 0; ch < 4; ++ch) { stA(0, 0, ch); stB(0, 0, ch); }
  asm volatile("s_waitcnt vmcnt(0)\n\ts_barrier" ::: "memory");

  for (int t = 0; t < KT; ++t) {
    const int c = t & 1;
    const char* bA = (const char*)&sA[c][0];
    const char* bB = (const char*)&sB[c][0];

    i32x4 af[8], bfr[4];
#pragma unroll
    for (int i = 0; i < 8; ++i) af[i] = *(const i32x4*)(bA + oA[i]);
#pragma unroll
    for (int j = 0; j < 4; ++j) bfr[j] = *(const i32x4*)(bB + oB[j]);

    if (t + 1 < KT) {
#pragma unroll
      for (int ch = 0; ch < 4; ++ch) { stA(c ^ 1, t + 1, ch); stB(c ^ 1, t + 1, ch); }
    }

    __builtin_amdgcn_s_setprio(1);
#pragma unroll
    for (int i = 0; i < 8; ++i)
#pragma unroll
      for (int j = 0; j < 4; ++j)
        acc[i][j] = mfma8i(af[i], bfr[j], acc[i][j]);
    __builtin_amdgcn_s_setprio(0);

#pragma unroll
    for (int i = 0; i < 8; ++i) af[i] = *(const i32x4*)(bA + (oA[i] ^ 64));
#pragma unroll
    for (int j = 0; j < 4; ++j) bfr[j] = *(const i32x4*)(bB + (oB[j] ^ 64));

    __builtin_amdgcn_s_setprio(1);
#pragma unroll
    for (int i = 0; i < 8; ++i)
#pragma unroll
      for (int j = 0; j < 4; ++j)
        acc[i][j] = mfma8i(af[i], bfr[j], acc[i][j]);
    __builtin_amdgcn_s_setprio(0);

    asm volatile("s_waitcnt vmcnt(0)\n\ts_barrier" ::: "memory");
  }

  // ---- dequant epilogue ----
  const int cb = n0 >> 10;
#pragma unroll
  for (int i = 0; i < 8; ++i) {
#pragma unroll
    for (int jj = 0; jj < 4; ++jj) {
      const int n = n0 + wn * 64 + jj * 16 + lr;
      const int m0r = m0 + wm * 128 + i * 16 + kg * 4;
      const float sbn = sb[n];
      const float4 s4 = *(const float4*)&sa[m0r];
      float de[4];
      de[0] = (float)acc[i][jj][0] * s4.x * sbn;
      de[1] = (float)acc[i][jj][1] * s4.y * sbn;
      de[2] = (float)acc[i][jj][2] * s4.z * sbn;
      de[3] = (float)acc[i][jj][3] * s4.w * sbn;
      if (MODE == 0) {
        const int nn = n & 1023;
        if (cb == 0) {
          const float b_ = bias0[nn];
#pragma unroll
          for (int r = 0; r < 4; ++r)
            Qo[(size_t)(m0r + r) * ADIM + nn] = (bf16)(de[r] + b_);
        } else if (cb == 1) {
          const float b_ = bias1[nn];
#pragma unroll
          for (int r = 0; r < 4; ++r) {
            float v = de[r] + b_;
            Ko[(size_t)(m0r + r) * ADIM + nn] = (bf16)(v > 0.f ? v + 1.f : __expf(v));
          }
        } else {
          const float b_ = bias2[nn];
          const int bb = m0r >> 11, t0c = m0r & 2047;
          bf16x4 pk;
#pragma unroll
          for (int r = 0; r < 4; ++r) pk[r] = (bf16)(de[r] + b_);
          *(bf16x4*)&Vto[((size_t)bb * ADIM + nn) * ASEQ + t0c] = pk;
        }
      } else {
        const float b_ = bias0[n];
#pragma unroll
        for (int r = 0; r < 4; ++r)
          outF[(size_t)(m0r + r) * ADIM + n] = de[r] + b_;
      }
    }
  }
}

// ------ windowed decay attention, 3-slot counted-vmcnt rings (r14-proven) ------
// NEW (T1): XCD-chunk swizzle on the T0-tile index — 32 tiles / 8 XCDs ->
// each XCD gets 4 CONSECUTIVE tiles (adjacent tiles share half their K/V
// window -> L2 hits instead of L3 refetch). x -> (x&7)*4 + (x>>3), bijective.
__global__ __launch_bounds__(256) void k_attn(
    const bf16* __restrict__ Qg, const bf16* __restrict__ Kg,
    const bf16* __restrict__ Vt, bf16* __restrict__ Rb,
    const float* __restrict__ decay_param)
{
  const int b = blockIdx.y;
  const int xt = (int)((blockIdx.x & 7) * 4 + (blockIdx.x >> 3));
  const int T0 = xt * 64;
  const int tid = threadIdx.x;
  const int l = tid & 63, w = tid >> 6;
  const int lr = l & 15, lk = (l >> 4) * 8;

  const float dp = decay_param[0];
  const float decay = 1.f / (1.f + __expf(-dp));
  const float l2d = __log2f(decay);

  __shared__ alignas(16) bf16 lQ[3][64 * 32];
  __shared__ alignas(16) bf16 lK[3][128 * 32];
  __shared__ alignas(16) bf16 lV[3][128 * 32];
  __shared__ alignas(16) bf16 lP[64 * 136];

  const bf16* Qb = Qg + (size_t)(b * ASEQ + T0) * ADIM;

  auto stageQK = [&](int buf, int k0) {
    {
      const bf16* g = Qb + (size_t)(w * 16 + (l >> 2)) * ADIM + k0 + (l & 3) * 8;
      gload_lds16(g, &lQ[buf][w * 16 * 32]);
    }
#pragma unroll
    for (int cc = 0; cc < 2; ++cc) {
      int c = 2 * w + cc;
      int sg = T0 - 64 + c * 16 + (l >> 2);
      if (sg < 0) sg = 0;
      const bf16* g = Kg + (size_t)(b * ASEQ + sg) * ADIM + k0 + (l & 3) * 8;
      gload_lds16(g, &lK[buf][c * 16 * 32]);
    }
  };

  f32x4 sc[4][2] = {};
  stageQK(0, 0);
  stageQK(1, 32);
  asm volatile("s_waitcnt vmcnt(3)\n\ts_barrier" ::: "memory");

  for (int kt = 0; kt < 32; ++kt) {
    const int cur = kt % 3;
    bf16x8 af[4], bfr[2];
#pragma unroll
    for (int i = 0; i < 4; ++i)
      af[i] = *(const bf16x8*)&lQ[cur][(i * 16 + lr) * 32 + lk];
#pragma unroll
    for (int j = 0; j < 2; ++j)
      bfr[j] = *(const bf16x8*)&lK[cur][(w * 32 + j * 16 + lr) * 32 + lk];

    const int tp = (kt + 2 < 32) ? kt + 2 : kt;
    stageQK((kt + 2) % 3, tp * 32);

#pragma unroll
    for (int i = 0; i < 4; ++i)
#pragma unroll
      for (int j = 0; j < 2; ++j)
        sc[i][j] = mfma16(af[i], bfr[j], sc[i][j]);

    asm volatile("s_waitcnt vmcnt(3)\n\ts_barrier" ::: "memory");
  }

  const int er = (l >> 4) * 4, ec = l & 15;
#pragma unroll
  for (int i = 0; i < 4; ++i)
#pragma unroll
    for (int j = 0; j < 2; ++j)
#pragma unroll
      for (int r = 0; r < 4; ++r) {
        int tl = i * 16 + er + r;
        int sl = w * 32 + j * 16 + ec;
        int sg = T0 - 64 + sl;
        int delta = (T0 + tl) - 1 - sg;
        float wgt = (delta >= 0 && delta < 64 && sg >= 0)
                        ? exp2f((float)delta * l2d) : 0.f;
        lP[tl * 136 + sl] = (bf16)(sc[i][j][r] * wgt);
      }

  auto stageV = [&](int buf, int g) {
    int nc = g >> 2, ks = g & 3;
#pragma unroll
    for (int cc = 0; cc < 2; ++cc) {
      int c = 2 * w + cc;
      int drow = nc * 128 + c * 16 + (l >> 2);
      int scol = T0 - 64 + ks * 32 + (l & 3) * 8;
      if (scol < 0) scol = 0;
      const bf16* gv = Vt + ((size_t)b * ADIM + drow) * ASEQ + scol;
      gload_lds16(gv, &lV[buf][c * 16 * 32]);
    }
  };

  stageV(0, 0);
  stageV(1, 1);
  asm volatile("s_waitcnt vmcnt(2) lgkmcnt(0)\n\ts_barrier" ::: "memory");

  f32x4 o[4][2] = {};
  for (int g = 0; g < 32; ++g) {
    const int cur = g % 3;
    const int nc = g >> 2, ks = g & 3;
    bf16x8 af[4], bfr[2];
#pragma unroll
    for (int i = 0; i < 4; ++i)
      af[i] = *(const bf16x8*)&lP[(i * 16 + lr) * 136 + ks * 32 + lk];
#pragma unroll
    for (int j = 0; j < 2; ++j)
      bfr[j] = *(const bf16x8*)&lV[cur][(w * 32 + j * 16 + lr) * 32 + lk];

    const int gp = (g + 2 < 32) ? g + 2 : g;
    stageV((g + 2) % 3, gp);

#pragma unroll
    for (int i = 0; i < 4; ++i)
#pragma unroll
      for (int j = 0; j < 2; ++j)
        o[i][j] = mfma16(af[i], bfr[j], o[i][j]);

    if (ks == 3) {
#pragma unroll
      for (int i = 0; i < 4; ++i)
#pragma unroll
        for (int j = 0; j < 2; ++j) {
#pragma unroll
          for (int r = 0; r < 4; ++r) {
            int tl = i * 16 + er + r;
            int dl = nc * 128 + w * 32 + j * 16 + ec;
            Rb[(size_t)(b * ASEQ + T0 + tl) * ADIM + dl] = (bf16)o[i][j][r];
          }
#pragma unroll
          for (int r = 0; r < 4; ++r) o[i][j][r] = 0.f;
        }
    }
    asm volatile("s_waitcnt vmcnt(2)\n\ts_barrier" ::: "memory");
  }
  asm volatile("s_waitcnt vmcnt(0)" ::: "memory");
}

extern "C" void kernel_launch(void* const* d_in, const int* in_sizes, int n_in,
                              void* d_out, int out_size, void* d_ws, size_t ws_size,
                              hipStream_t stream) {
  const float* x  = (const float*)d_in[0];
  const float* Wq = (const float*)d_in[1];
  const float* bq = (const float*)d_in[2];
  const float* Wk = (const float*)d_in[3];
  const float* bk = (const float*)d_in[4];
  const float* Wv = (const float*)d_in[5];
  const float* bv = (const float*)d_in[6];
  const float* Wo = (const float*)d_in[7];
  const float* bo = (const float*)d_in[8];
  const float* dp = (const float*)d_in[9];
  float* out = (float*)d_out;

  char* ws = (char*)d_ws;
  signed char* Xq  = (signed char*)(ws + ((size_t)0 << 20));   // 16 MB
  signed char* Rq  = Xq;                                       // alias (Xq dead)
  float*       sx  = (float*)(ws + ((size_t)16 << 20));        // 64 KB
  float*       sxr = sx;
  signed char* WcQ = (signed char*)(ws + ((size_t)17 << 20));  // 3 MB
  float*       swc = (float*)(ws + ((size_t)20 << 20));        // 12 KB
  signed char* WoQ = (signed char*)(ws + ((size_t)21 << 20));  // 1 MB
  float*       swo = (float*)(ws + ((size_t)22 << 20));        // 4 KB
  bf16* Qb  = (bf16*)(ws + ((size_t)32 << 20));
  bf16* Kb  = (bf16*)(ws + ((size_t)64 << 20));
  bf16* Vtb = (bf16*)(ws + ((size_t)96 << 20));                // [8][1024][2048]
  bf16* Rbb = (bf16*)(ws + ((size_t)128 << 20));
  bf16* WcT = (bf16*)(ws + ((size_t)160 << 20));               // [3072][1024] bf16
  bf16* WoT = (bf16*)(ws + ((size_t)166 << 20));               // [1024][1024] bf16

  k_prep_w<<<1024, 256, 0, stream>>>(Wq, Wk, Wv, Wo, WcT, WoT);
  k_q<<<5120, 256, 0, stream>>>(x, WcT, WoT, Xq, sx, WcQ, swc, WoQ, swo);
  k_gi8<0><<<768, 512, 0, stream>>>(
      Xq, WcQ, sx, swc, bq, bk, bv, Qb, Kb, Vtb, nullptr, 12);
  k_attn<<<dim3(32, 8), 256, 0, stream>>>(Qb, Kb, Vtb, Rbb, dp);
  k_qr<<<4096, 256, 0, stream>>>(Rbb, Rq, sxr);
  k_gi8<1><<<256, 512, 0, stream>>>(
      Rq, WoQ, sxr, swo, bo, nullptr, nullptr, nullptr, nullptr, nullptr, out, 4);
}